// Round 1
// baseline (214.914 us; speedup 1.0000x reference)
//
#include <hip/hip_runtime.h>

// DILATE loss: alpha*soft-DTW(value) + (1-alpha)*<softDTW-grad, Omega>
// B=64, T=128, C=4  ->  M = B*C = 256 independent sequences, N = 128.
// One block per sequence; 128 threads = one thread per DTW row.
// R matrix (129x129) in LDS (stride 130 => diagonal access hits distinct
// banks: per-thread addr stride 129 == 1 mod 32). Backward E uses 3 rolling
// diagonal buffers (never materialized).

#define TN 128      // sequence length N
#define RS 130      // LDS row stride for R (conflict-free diagonals)
#define BATCH 64
#define CH 4

__global__ __launch_bounds__(TN)
void dilate_softdtw_kernel(const float* __restrict__ outputs,
                           const float* __restrict__ targets,
                           float* __restrict__ out) {
  __shared__ float Rs[(TN + 1) * RS];   // 129*130*4 = 67080 B
  __shared__ float t_s[TN];
  __shared__ float o_s[TN];
  __shared__ float eA[TN + 2];
  __shared__ float eB[TN + 2];
  __shared__ float eC[TN + 2];
  __shared__ float red[2];

  const float GAMMA = 0.01f;
  const float INVG  = 100.0f;
  const float BIG   = 100000000.0f;

  const int m   = blockIdx.x;     // sequence index, 0..255
  const int b   = m >> 2;         // m / C
  const int c   = m & 3;          // m % C
  const int tid = threadIdx.x;    // 0..127

  // t[i] = targets[b][i][c], o[j] = outputs[b][j][c]
  const float* tb = targets + (size_t)b * (TN * CH) + c;
  const float* ob = outputs + (size_t)b * (TN * CH) + c;
  t_s[tid] = tb[tid * CH];
  o_s[tid] = ob[tid * CH];

  // R boundaries: R[0][0]=0, R[0][j]=R[i][0]=BIG
  Rs[tid + 1]        = BIG;   // row 0, cols 1..128
  Rs[(tid + 1) * RS] = BIG;   // col 0, rows 1..128
  if (tid == 0) Rs[0] = 0.0f;
  eA[tid] = 0.0f; eB[tid] = 0.0f; eC[tid] = 0.0f;
  if (tid < 2) { eA[TN + tid] = 0.0f; eB[TN + tid] = 0.0f; eC[TN + tid] = 0.0f; }
  __syncthreads();

  const int i = tid + 1;          // 1-indexed row owned by this thread
  const float ti = t_s[tid];      // t[i]

  // ---------------- forward: R[i][j] = D[i][j] + softmin3 ----------------
  #pragma unroll 1
  for (int d = 2; d <= 2 * TN; ++d) {
    const int j = d - i;
    if (j >= 1 && j <= TN) {
      const float rd = Rs[(i - 1) * RS + (j - 1)];
      const float ru = Rs[(i - 1) * RS + j];
      const float rl = Rs[i * RS + (j - 1)];
      float mn = fminf(rd, fminf(ru, rl));
      // stable softmin: args of exp are <= 0
      const float s = mn - GAMMA * logf(expf((mn - rd) * INVG) +
                                        expf((mn - ru) * INVG) +
                                        expf((mn - rl) * INVG));
      const float diff = ti - o_s[j - 1];
      Rs[i * RS + j] = diff * diff + s;
    }
    __syncthreads();
  }

  // ---------------- backward: E recursion on rolling diagonals ----------------
  // E[i][j] = E[i+1][j]   * exp((R[i+1][j]   - R[i][j] - D[i+1][j])  /g)
  //         + E[i][j+1]   * exp((R[i][j+1]   - R[i][j] - D[i][j+1])  /g)
  //         + E[i+1][j+1] * exp((R[i+1][j+1] - R[i][j] - D[i+1][j+1])/g)
  // e1 = diag d+1 (indexed by row), e2 = diag d+2.
  const float tip1 = (tid + 1 < TN) ? t_s[tid + 1] : 0.0f;  // t[i+1]
  float* ecur = eA; float* e1 = eB; float* e2 = eC;
  float acc = 0.0f;   // sum of E[i][j] * (i-j)^2 over this thread's cells

  #pragma unroll 1
  for (int d = 2 * TN; d >= 2; --d) {
    const int j = d - i;
    float v = 0.0f;
    if (j >= 1 && j <= TN) {
      if (i == TN && j == TN) {
        v = 1.0f;
      } else {
        const float rij = Rs[i * RS + j];
        const float oj  = o_s[j - 1];                 // o[j]
        if (i < TN) {
          float du = tip1 - oj; du *= du;             // D[i+1][j]
          v += e1[i + 1] * expf((Rs[(i + 1) * RS + j] - rij - du) * INVG);
        }
        if (j < TN) {
          const float op = o_s[j];                    // o[j+1]
          float dl = ti - op; dl *= dl;               // D[i][j+1]
          v += e1[i] * expf((Rs[i * RS + (j + 1)] - rij - dl) * INVG);
          if (i < TN) {
            float dd = tip1 - op; dd *= dd;           // D[i+1][j+1]
            v += e2[i + 1] * expf((Rs[(i + 1) * RS + (j + 1)] - rij - dd) * INVG);
          }
        }
      }
      const float dij = (float)(i - j);
      acc += v * dij * dij;
    }
    ecur[i] = v;   // also clears stale entries for rows not on this diagonal
    float* tmp = e2; e2 = e1; e1 = ecur; ecur = tmp;
    __syncthreads();
  }

  // ---------------- reduce & accumulate scalar loss ----------------
  #pragma unroll
  for (int off = 32; off > 0; off >>= 1) acc += __shfl_down(acc, off, 64);
  if ((tid & 63) == 0) red[tid >> 6] = acc;
  __syncthreads();
  if (tid == 0) {
    const float total = red[0] + red[1];
    // ALPHA * vals/B + (1-ALPHA) * sum(E*Omega)/(B*T*T), ALPHA = 0.5
    const float partial = 0.5f * (Rs[TN * RS + TN] / (float)BATCH)
                        + 0.5f * (total / (float)(BATCH * TN * TN));
    atomicAdd(out, partial);
  }
}

extern "C" void kernel_launch(void* const* d_in, const int* in_sizes, int n_in,
                              void* d_out, int out_size, void* d_ws, size_t ws_size,
                              hipStream_t stream) {
  const float* outputs = (const float*)d_in[0];   // [64,128,4]
  const float* targets = (const float*)d_in[1];   // [64,128,4]
  float* out = (float*)d_out;                     // scalar fp32
  (void)in_sizes; (void)n_in; (void)out_size; (void)d_ws; (void)ws_size;

  // d_out is poisoned to 0xAA before every timed launch — zero it ourselves.
  hipMemsetAsync(out, 0, sizeof(float), stream);
  dilate_softdtw_kernel<<<dim3(256), dim3(TN), 0, stream>>>(outputs, targets, out);
}